// Round 5
// baseline (830.636 us; speedup 1.0000x reference)
//
#include <hip/hip_runtime.h>
#include <hip/hip_bf16.h>

// MoE top-2 of 8 experts. N=8192 tokens, D=1024, F=2048.
// R5: (a) router rewritten: block-level ballot ranking, 8 atomics/block
//     (was 2 atomics/token onto one cache line = 200us of serialized RMW).
//     (b) grouped GEMM moved to 256x256 tile, BK=64, 8 waves, 2 LDS buffers,
//     counted s_waitcnt vmcnt(8) pipeline (loads stay in flight across the
//     barrier; vmcnt(0) only at the last K-tile). XOR-involution chunk
//     swizzle (8 chunks/row) keeps staging coalesced and ds_read conflict-free.

#define N_TOK 8192
#define DIM   1024
#define FF    2048
#define NE    8

typedef unsigned short ushort_t;
typedef __bf16 bf16x8 __attribute__((ext_vector_type(8)));
typedef float  f32x4  __attribute__((ext_vector_type(4)));
typedef unsigned short u16x8 __attribute__((ext_vector_type(8)));

__device__ __forceinline__ ushort_t f2bf(float f) {
    union { float f; unsigned int u; } v; v.f = f;
    unsigned int r = (v.u + 0x7FFFu + ((v.u >> 16) & 1u)) >> 16;  // RNE
    return (ushort_t)r;
}

__device__ __forceinline__ void gload_lds16(const ushort_t* g, ushort_t* l) {
    __builtin_amdgcn_global_load_lds(
        (const __attribute__((address_space(1))) void*)g,
        (__attribute__((address_space(3))) void*)l,
        16, 0, 0);
}

// ---------------- convert x fp32 -> bf16 ----------------
__global__ __launch_bounds__(256) void convert_x_kernel(
    const float* __restrict__ x, ushort_t* __restrict__ xb)
{
    size_t i = ((size_t)blockIdx.x * 256 + threadIdx.x) * 8;
    float4 a = *reinterpret_cast<const float4*>(x + i);
    float4 b = *reinterpret_cast<const float4*>(x + i + 4);
    u16x8 o;
    o[0] = f2bf(a.x); o[1] = f2bf(a.y); o[2] = f2bf(a.z); o[3] = f2bf(a.w);
    o[4] = f2bf(b.x); o[5] = f2bf(b.y); o[6] = f2bf(b.z); o[7] = f2bf(b.w);
    *reinterpret_cast<u16x8*>(xb + i) = o;
}

// ---------------- tiled transpose + convert: in [E][R][C] f32 -> out [E][C][R] bf16 ----
__global__ void transpose_conv_kernel(
    const float* __restrict__ in, ushort_t* __restrict__ out, int R, int C)
{
    __shared__ float tile[32][33];
    const int e = blockIdx.z;
    const float* I = in + (size_t)e * R * C;
    ushort_t*    O = out + (size_t)e * R * C;
    const int c0 = blockIdx.x * 32, r0 = blockIdx.y * 32;
    const int tx = threadIdx.x, ty = threadIdx.y;   // 32 x 8
#pragma unroll
    for (int j = 0; j < 32; j += 8)
        tile[ty + j][tx] = I[(size_t)(r0 + ty + j) * C + (c0 + tx)];
    __syncthreads();
#pragma unroll
    for (int j = 0; j < 32; j += 8)
        O[(size_t)(c0 + ty + j) * R + (r0 + tx)] = f2bf(tile[tx][ty + j]);
}

// ---------------- router: 128 blocks x 64 tokens; ballot ranking, 8 atomics/blk ----
__global__ __launch_bounds__(256) void router_kernel(
    const float* __restrict__ x, const float* __restrict__ Wr, const float* __restrict__ br,
    int* __restrict__ cnt, int* __restrict__ tok_list, float* __restrict__ w_list)
{
    __shared__ int   se0[64], se1[64];
    __shared__ float sw0[64], sw1[64];

    const int wid  = threadIdx.x >> 6;
    const int lane = threadIdx.x & 63;
    const int tblk = blockIdx.x * 64;

    // each wave computes 16 tokens sequentially (exact fp32 logits)
    for (int i = 0; i < 16; ++i) {
        const int li = wid * 16 + i;            // token slot in block
        const int t  = tblk + li;
        const float* xr = x + (size_t)t * DIM;

        float acc[NE];
#pragma unroll
        for (int e = 0; e < NE; ++e) acc[e] = 0.f;
        for (int d = lane; d < DIM; d += 64) {
            float xv = xr[d];
            const float4* w4 = reinterpret_cast<const float4*>(Wr + (size_t)d * NE);
            float4 w0 = w4[0], w1 = w4[1];
            acc[0] += xv * w0.x; acc[1] += xv * w0.y; acc[2] += xv * w0.z; acc[3] += xv * w0.w;
            acc[4] += xv * w1.x; acc[5] += xv * w1.y; acc[6] += xv * w1.z; acc[7] += xv * w1.w;
        }
#pragma unroll
        for (int e = 0; e < NE; ++e) {
            for (int off = 32; off > 0; off >>= 1)
                acc[e] += __shfl_down(acc[e], off, 64);
        }
        if (lane == 0) {
            float l[NE];
#pragma unroll
            for (int e = 0; e < NE; ++e) l[e] = acc[e] + br[e];
            float mx = l[0];
#pragma unroll
            for (int e = 1; e < NE; ++e) mx = fmaxf(mx, l[e]);
            float p[NE], s = 0.f;
#pragma unroll
            for (int e = 0; e < NE; ++e) { p[e] = expf(l[e] - mx); s += p[e]; }
            float inv = 1.f / s;
            // top-2, lowest-index-on-tie (strict >) to match jax.lax.top_k
            int e0 = 0;
#pragma unroll
            for (int e = 1; e < NE; ++e) if (l[e] > l[e0]) e0 = e;
            int e1 = (e0 == 0) ? 1 : 0;
#pragma unroll
            for (int e = 0; e < NE; ++e) if (e != e0 && l[e] > l[e1]) e1 = e;
            se0[li] = e0; sw0[li] = p[e0] * inv;
            se1[li] = e1; sw1[li] = p[e1] * inv;
        }
    }
    __syncthreads();

    // wave 0: rank 64 tokens x 2 slots per expert, reserve ranges, scatter
    if (threadIdx.x < 64) {
        const int t  = tblk + lane;
        const int e0 = se0[lane], e1 = se1[lane];
        const unsigned long long below = ((unsigned long long)1 << lane) - 1;
        int p0 = 0, p1 = 0;
#pragma unroll
        for (int e = 0; e < NE; ++e) {
            unsigned long long m0 = __ballot(e0 == e);
            unsigned long long m1 = __ballot(e1 == e);
            int c = __popcll(m0) + __popcll(m1);
            int b = 0;
            if (lane == e && c) b = atomicAdd(&cnt[e], c);
            b = __shfl(b, e, 64);
            if (e0 == e) p0 = b + __popcll(m0 & below);
            if (e1 == e) p1 = b + __popcll(m0) + __popcll(m1 & below);
        }
        tok_list[e0 * N_TOK + p0] = t;  w_list[e0 * N_TOK + p0] = sw0[lane];
        tok_list[e1 * N_TOK + p1] = t;  w_list[e1 * N_TOK + p1] = sw1[lane];
    }
}

__global__ void scan_kernel(const int* __restrict__ cnt, int* __restrict__ offs)
{
    if (threadIdx.x == 0 && blockIdx.x == 0) {
        int s = 0;
        for (int e = 0; e < NE; ++e) { offs[e] = s; s += cnt[e]; }
        offs[NE] = s;
    }
}

// ------- grouped GEMM, 256x256 tile, BK=64, 8 waves (2x4), per-wave 128x64 -------
// LDS: 2 buffers. Slot layout per buffer: [row 0..255][slot 0..7][8 bf16];
// slot s of row r holds global chunk (s ^ (r&7)) (involution; read applies same).
// Pipeline: STAGE(t+1) -> vmcnt(8) -> barrier -> COMPUTE(t) -> barrier.
// MODE 0: A gathered via tok_list, epilogue bias+GELU -> h (bf16), XCD swizzle
// MODE 1: A = h rows (contiguous), epilogue bias, * w, atomicAdd -> out, no swizzle
template <int MODE>
__global__ __launch_bounds__(512, 2) void moe_gemm_kernel(
    const ushort_t* __restrict__ A,
    const ushort_t* __restrict__ Bt,    // [NE][NCOL][K] bf16 (K contiguous)
    const float*    __restrict__ bias,  // [NE][NCOL]
    const int*      __restrict__ cnt,
    const int*      __restrict__ offs,
    const int*      __restrict__ tok_list,
    const float*    __restrict__ w_list,
    ushort_t*       __restrict__ hout,
    float*          __restrict__ out,
    int K, int NCOL)
{
    const int e = blockIdx.z;
    const int cnt_e = cnt[e];

    int wg;
    if (MODE == 0) {
        const int cpx = gridDim.x >> 3;           // nb-owned XCD chunks (balanced)
        wg = (blockIdx.x & 7) * cpx + (blockIdx.x >> 3);
    } else {
        wg = blockIdx.x;                          // round-robin (balanced)
    }
    const int mb = wg & 31;                       // 32 m-tiles (8192/256)
    const int nb = wg >> 5;

    const int m0 = mb * 256;
    if (m0 >= cnt_e) return;
    const int n0 = nb * 256;
    const int offs_e = offs[e];

    __shared__ ushort_t As[2][256 * 64];
    __shared__ ushort_t Bs[2][256 * 64];

    const int tid = threadIdx.x;

    // per-thread staging sources: c = tid + 512*j; row=c>>3, slot=c&7,
    // global chunk = slot ^ (row&7)  (inverse swizzle at the source)
    unsigned int asrc[4], bsrc[4];
#pragma unroll
    for (int j = 0; j < 4; ++j) {
        int c = tid + 512 * j;
        int row  = c >> 3;
        int gch  = (c & 7) ^ (row & 7);
        int entry = m0 + row;
        unsigned int arow;
        if (MODE == 0) {
            int tok = (entry < cnt_e) ? tok_list[e * N_TOK + entry] : 0;
            arow = (unsigned int)tok * K;
        } else {
            arow = (unsigned int)(offs_e + entry) * K;   // slack rows in h
        }
        asrc[j] = arow + gch * 8;
        int col = n0 + row;
        bsrc[j] = (unsigned int)(e * NCOL + col) * K + gch * 8;
    }

    f32x4 acc[8][4];
#pragma unroll
    for (int m = 0; m < 8; ++m)
#pragma unroll
        for (int n = 0; n < 4; ++n)
            acc[m][n] = (f32x4){0.f, 0.f, 0.f, 0.f};

    const int lane = tid & 63;
    const int wid  = tid >> 6;
    const int wr = (wid >> 2) * 128;   // wave rows [wr, wr+128)
    const int wc = (wid & 3) * 64;     // wave cols [wc, wc+64)
    const int la = lane & 15;
    const int kc = lane >> 4;          // k-chunk within 32-k slice

    auto STAGE = [&](int t, int b) {
        const int k0 = t * 64;
#pragma unroll
        for (int j = 0; j < 4; ++j) {
            gload_lds16(A  + (size_t)asrc[j] + k0, &As[b][(tid + 512 * j) * 8]);
            gload_lds16(Bt + (size_t)bsrc[j] + k0, &Bs[b][(tid + 512 * j) * 8]);
        }
    };

    auto COMPUTE = [&](int b) {
#pragma unroll
        for (int s = 0; s < 2; ++s) {
            bf16x8 af[8], bfr[4];
#pragma unroll
            for (int m = 0; m < 8; ++m) {
                int r = wr + m * 16 + la;
                af[m] = *reinterpret_cast<const bf16x8*>(
                    &As[b][(r * 8 + ((s * 4 + kc) ^ (r & 7))) * 8]);
            }
#pragma unroll
            for (int n = 0; n < 4; ++n) {
                int ccol = wc + n * 16 + la;
                bfr[n] = *reinterpret_cast<const bf16x8*>(
                    &Bs[b][(ccol * 8 + ((s * 4 + kc) ^ (ccol & 7))) * 8]);
            }
#pragma unroll
            for (int m = 0; m < 8; ++m)
#pragma unroll
                for (int n = 0; n < 4; ++n)
                    acc[m][n] = __builtin_amdgcn_mfma_f32_16x16x32_bf16(
                        af[m], bfr[n], acc[m][n], 0, 0, 0);
        }
    };

    const int nt = K / 64;
    STAGE(0, 0);
    for (int t = 0; t < nt - 1; ++t) {
        STAGE(t + 1, (t + 1) & 1);
        asm volatile("s_waitcnt vmcnt(8)" ::: "memory");  // tile t landed; t+1 in flight
        __builtin_amdgcn_s_barrier();
        COMPUTE(t & 1);
        __builtin_amdgcn_s_barrier();
    }
    asm volatile("s_waitcnt vmcnt(0)" ::: "memory");
    __builtin_amdgcn_s_barrier();
    COMPUTE((nt - 1) & 1);

    // epilogue: C/D layout col = lane&15, row = (lane>>4)*4 + j (HW-verified)
#pragma unroll
    for (int m = 0; m < 8; ++m) {
        int rbase = wr + m * 16 + (lane >> 4) * 4;
#pragma unroll
        for (int n = 0; n < 4; ++n) {
            int gcol = n0 + wc + n * 16 + la;
            float bi = bias[(size_t)e * NCOL + gcol];
#pragma unroll
            for (int jj = 0; jj < 4; ++jj) {
                int entry = m0 + rbase + jj;
                if (entry < cnt_e) {
                    float v = acc[m][n][jj] + bi;
                    if (MODE == 0) {
                        // jax.nn.gelu approximate=True (tanh form)
                        float u = 0.7978845608028654f * (v + 0.044715f * v * v * v);
                        float g = 0.5f * v * (1.f + tanhf(u));
                        hout[(size_t)(offs_e + entry) * NCOL + gcol] = f2bf(g);
                    } else {
                        int tok  = tok_list[e * N_TOK + entry];
                        float w  = w_list  [e * N_TOK + entry];
                        atomicAdd(&out[(size_t)tok * NCOL + gcol], w * v);
                    }
                }
            }
        }
    }
}

extern "C" void kernel_launch(void* const* d_in, const int* in_sizes, int n_in,
                              void* d_out, int out_size, void* d_ws, size_t ws_size,
                              hipStream_t stream)
{
    const float* x  = (const float*)d_in[0];
    const float* Wr = (const float*)d_in[1];
    const float* br = (const float*)d_in[2];
    const float* W1 = (const float*)d_in[3];
    const float* b1 = (const float*)d_in[4];
    const float* W2 = (const float*)d_in[5];
    const float* b2 = (const float*)d_in[6];
    float* out = (float*)d_out;

    // workspace layout (~153 MB total)
    char* ws = (char*)d_ws;
    size_t off = 0;
    auto alloc = [&](size_t bytes) -> void* {
        void* p = ws + off;
        off = (off + bytes + 255) & ~(size_t)255;
        return p;
    };
    ushort_t* xb  = (ushort_t*)alloc((size_t)N_TOK * DIM * 2);            // 16 MB
    ushort_t* w1t = (ushort_t*)alloc((size_t)NE * DIM * FF * 2);          // 32 MB  [E][F][D]
    ushort_t* w2t = (ushort_t*)alloc((size_t)NE * DIM * FF * 2);          // 32 MB  [E][D][F]
    ushort_t* h   = (ushort_t*)alloc(((size_t)2 * N_TOK + 256) * FF * 2); // 65 MB (+slack rows)
    int*      cnt = (int*)alloc(NE * sizeof(int));
    int*      offs= (int*)alloc((NE + 1) * sizeof(int));
    int*   tok_list = (int*)alloc((size_t)NE * N_TOK * sizeof(int));
    float* w_list   = (float*)alloc((size_t)NE * N_TOK * sizeof(float));
    (void)ws_size; (void)in_sizes; (void)n_in;

    hipMemsetAsync(out, 0, (size_t)out_size * sizeof(float), stream);
    hipMemsetAsync(cnt, 0, NE * sizeof(int), stream);

    convert_x_kernel<<<(N_TOK * DIM) / (8 * 256), 256, 0, stream>>>(x, xb);
    transpose_conv_kernel<<<dim3(FF / 32, DIM / 32, NE), dim3(32, 8), 0, stream>>>(W1, w1t, DIM, FF);
    transpose_conv_kernel<<<dim3(DIM / 32, FF / 32, NE), dim3(32, 8), 0, stream>>>(W2, w2t, FF, DIM);
    router_kernel<<<N_TOK / 64, 256, 0, stream>>>(x, Wr, br, cnt, tok_list, w_list);
    scan_kernel<<<1, 64, 0, stream>>>(cnt, offs);

    moe_gemm_kernel<0><<<dim3(32 * (FF / 256), 1, NE), 512, 0, stream>>>(
        xb, w1t, b1, cnt, offs, tok_list, w_list, h, nullptr, DIM, FF);
    moe_gemm_kernel<1><<<dim3(32 * (DIM / 256), 1, NE), 512, 0, stream>>>(
        h, w2t, b2, cnt, offs, tok_list, w_list, nullptr, out, FF, DIM);
}

// Round 6
// 566.931 us; speedup vs baseline: 1.4651x; 1.4651x over previous
//
#include <hip/hip_runtime.h>
#include <hip/hip_bf16.h>

// MoE top-2 of 8 experts. N=8192 tokens, D=1024, F=2048.
// R6: GEMM back to the measured R4 structure (128x128, BK=32, 3 LDS buffers,
//     2-deep prefetch, 3 blocks/CU) with ONE change: single s_barrier per
//     K-step with counted s_waitcnt vmcnt(4) AFTER compute (T3 minimal form;
//     never drains to 0 in steady state). Router stays R5 (ballot ranking).

#define N_TOK 8192
#define DIM   1024
#define FF    2048
#define NE    8

typedef unsigned short ushort_t;
typedef __bf16 bf16x8 __attribute__((ext_vector_type(8)));
typedef float  f32x4  __attribute__((ext_vector_type(4)));
typedef unsigned short u16x8 __attribute__((ext_vector_type(8)));

__device__ __forceinline__ ushort_t f2bf(float f) {
    union { float f; unsigned int u; } v; v.f = f;
    unsigned int r = (v.u + 0x7FFFu + ((v.u >> 16) & 1u)) >> 16;  // RNE
    return (ushort_t)r;
}

__device__ __forceinline__ void gload_lds16(const ushort_t* g, ushort_t* l) {
    __builtin_amdgcn_global_load_lds(
        (const __attribute__((address_space(1))) void*)g,
        (__attribute__((address_space(3))) void*)l,
        16, 0, 0);
}

// ---------------- convert x fp32 -> bf16 ----------------
__global__ __launch_bounds__(256) void convert_x_kernel(
    const float* __restrict__ x, ushort_t* __restrict__ xb)
{
    size_t i = ((size_t)blockIdx.x * 256 + threadIdx.x) * 8;
    float4 a = *reinterpret_cast<const float4*>(x + i);
    float4 b = *reinterpret_cast<const float4*>(x + i + 4);
    u16x8 o;
    o[0] = f2bf(a.x); o[1] = f2bf(a.y); o[2] = f2bf(a.z); o[3] = f2bf(a.w);
    o[4] = f2bf(b.x); o[5] = f2bf(b.y); o[6] = f2bf(b.z); o[7] = f2bf(b.w);
    *reinterpret_cast<u16x8*>(xb + i) = o;
}

// ---------------- tiled transpose + convert: in [E][R][C] f32 -> out [E][C][R] bf16 ----
__global__ void transpose_conv_kernel(
    const float* __restrict__ in, ushort_t* __restrict__ out, int R, int C)
{
    __shared__ float tile[32][33];
    const int e = blockIdx.z;
    const float* I = in + (size_t)e * R * C;
    ushort_t*    O = out + (size_t)e * R * C;
    const int c0 = blockIdx.x * 32, r0 = blockIdx.y * 32;
    const int tx = threadIdx.x, ty = threadIdx.y;   // 32 x 8
#pragma unroll
    for (int j = 0; j < 32; j += 8)
        tile[ty + j][tx] = I[(size_t)(r0 + ty + j) * C + (c0 + tx)];
    __syncthreads();
#pragma unroll
    for (int j = 0; j < 32; j += 8)
        O[(size_t)(c0 + ty + j) * R + (r0 + tx)] = f2bf(tile[tx][ty + j]);
}

// ---------------- router: 128 blocks x 64 tokens; ballot ranking, 8 atomics/blk ----
__global__ __launch_bounds__(256) void router_kernel(
    const float* __restrict__ x, const float* __restrict__ Wr, const float* __restrict__ br,
    int* __restrict__ cnt, int* __restrict__ tok_list, float* __restrict__ w_list)
{
    __shared__ int   se0[64], se1[64];
    __shared__ float sw0[64], sw1[64];

    const int wid  = threadIdx.x >> 6;
    const int lane = threadIdx.x & 63;
    const int tblk = blockIdx.x * 64;

    for (int i = 0; i < 16; ++i) {
        const int li = wid * 16 + i;            // token slot in block
        const int t  = tblk + li;
        const float* xr = x + (size_t)t * DIM;

        float acc[NE];
#pragma unroll
        for (int e = 0; e < NE; ++e) acc[e] = 0.f;
        for (int d = lane; d < DIM; d += 64) {
            float xv = xr[d];
            const float4* w4 = reinterpret_cast<const float4*>(Wr + (size_t)d * NE);
            float4 w0 = w4[0], w1 = w4[1];
            acc[0] += xv * w0.x; acc[1] += xv * w0.y; acc[2] += xv * w0.z; acc[3] += xv * w0.w;
            acc[4] += xv * w1.x; acc[5] += xv * w1.y; acc[6] += xv * w1.z; acc[7] += xv * w1.w;
        }
#pragma unroll
        for (int e = 0; e < NE; ++e) {
            for (int off = 32; off > 0; off >>= 1)
                acc[e] += __shfl_down(acc[e], off, 64);
        }
        if (lane == 0) {
            float l[NE];
#pragma unroll
            for (int e = 0; e < NE; ++e) l[e] = acc[e] + br[e];
            float mx = l[0];
#pragma unroll
            for (int e = 1; e < NE; ++e) mx = fmaxf(mx, l[e]);
            float p[NE], s = 0.f;
#pragma unroll
            for (int e = 0; e < NE; ++e) { p[e] = expf(l[e] - mx); s += p[e]; }
            float inv = 1.f / s;
            // top-2, lowest-index-on-tie (strict >) to match jax.lax.top_k
            int e0 = 0;
#pragma unroll
            for (int e = 1; e < NE; ++e) if (l[e] > l[e0]) e0 = e;
            int e1 = (e0 == 0) ? 1 : 0;
#pragma unroll
            for (int e = 0; e < NE; ++e) if (e != e0 && l[e] > l[e1]) e1 = e;
            se0[li] = e0; sw0[li] = p[e0] * inv;
            se1[li] = e1; sw1[li] = p[e1] * inv;
        }
    }
    __syncthreads();

    // wave 0: rank 64 tokens x 2 slots per expert, reserve ranges, scatter
    if (threadIdx.x < 64) {
        const int t  = tblk + lane;
        const int e0 = se0[lane], e1 = se1[lane];
        const unsigned long long below = ((unsigned long long)1 << lane) - 1;
        int p0 = 0, p1 = 0;
#pragma unroll
        for (int e = 0; e < NE; ++e) {
            unsigned long long m0 = __ballot(e0 == e);
            unsigned long long m1 = __ballot(e1 == e);
            int c = __popcll(m0) + __popcll(m1);
            int b = 0;
            if (lane == e && c) b = atomicAdd(&cnt[e], c);
            b = __shfl(b, e, 64);
            if (e0 == e) p0 = b + __popcll(m0 & below);
            if (e1 == e) p1 = b + __popcll(m0) + __popcll(m1 & below);
        }
        tok_list[e0 * N_TOK + p0] = t;  w_list[e0 * N_TOK + p0] = sw0[lane];
        tok_list[e1 * N_TOK + p1] = t;  w_list[e1 * N_TOK + p1] = sw1[lane];
    }
}

__global__ void scan_kernel(const int* __restrict__ cnt, int* __restrict__ offs)
{
    if (threadIdx.x == 0 && blockIdx.x == 0) {
        int s = 0;
        for (int e = 0; e < NE; ++e) { offs[e] = s; s += cnt[e]; }
        offs[NE] = s;
    }
}

// ---------------- grouped GEMM, 128x128 tile, BK=32, 4 waves (2x2), acc 4x4 ----
// LDS: 3 buffers (2-deep pipeline). Slot c of a buffer holds global
// (row=c>>2, chunk=(c&3)^((row>>1)&3)); fragment read applies the same XOR.
// K-loop: [STAGE(t+2)] -> COMPUTE(t) -> vmcnt(4 or 0) -> barrier  (ONE barrier)
// MODE 0: A = xb gathered via tok_list, epilogue bias+GELU -> h (bf16)
// MODE 1: A = h rows (contiguous per expert), epilogue bias, * w, atomicAdd -> out
template <int MODE>
__global__ __launch_bounds__(256) void moe_gemm_kernel(
    const ushort_t* __restrict__ A,
    const ushort_t* __restrict__ Bt,    // [NE][NCOL][K] bf16 (K contiguous)
    const float*    __restrict__ bias,  // [NE][NCOL]
    const int*      __restrict__ cnt,
    const int*      __restrict__ offs,
    const int*      __restrict__ tok_list,
    const float*    __restrict__ w_list,
    ushort_t*       __restrict__ hout,
    float*          __restrict__ out,
    int K, int NCOL)
{
    const int e = blockIdx.z;
    const int cnt_e = cnt[e];

    int wg;
    if (MODE == 0) {
        const int cpx = gridDim.x >> 3;   // chunked XCD swizzle (bijective)
        wg = (blockIdx.x & 7) * cpx + (blockIdx.x >> 3);
    } else {
        wg = blockIdx.x;
    }
    const int mb = wg & 63;               // 64 m-tiles (8192/128)
    const int nb = wg >> 6;

    const int m0 = mb * 128;
    if (m0 >= cnt_e) return;              // early-exit unused tiles
    const int n0 = nb * 128;
    const int offs_e = offs[e];

    __shared__ ushort_t As[3][128 * 32];
    __shared__ ushort_t Bs[3][128 * 32];

    const int tid = threadIdx.x;

    // per-thread global source offsets (elements); XOR-swizzled chunk within row
    size_t asrc[2], bsrc[2];
#pragma unroll
    for (int j = 0; j < 2; ++j) {
        int c = tid + 256 * j;
        int row   = c >> 2;
        int chunk = (c & 3) ^ ((row >> 1) & 3);
        int entry = m0 + row;
        size_t arow;
        if (MODE == 0) {
            int tok = (entry < cnt_e) ? tok_list[e * N_TOK + entry] : 0;
            arow = (size_t)tok * K;
        } else {
            arow = (size_t)(offs_e + entry) * K;   // slack rows allocated in h
        }
        asrc[j] = arow + (size_t)chunk * 8;
        int col = n0 + row;
        bsrc[j] = ((size_t)e * NCOL + col) * K + (size_t)chunk * 8;
    }

    f32x4 acc[4][4];
#pragma unroll
    for (int m = 0; m < 4; ++m)
#pragma unroll
        for (int n = 0; n < 4; ++n)
            acc[m][n] = (f32x4){0.f, 0.f, 0.f, 0.f};

    const int lane = tid & 63;
    const int wid  = tid >> 6;
    const int wr = (wid >> 1) * 64;
    const int wc = (wid & 1) * 64;
    const int la = lane & 15;
    const int kc = lane >> 4;          // k-chunk 0..3 owned by this lane group

    auto STAGE = [&](int t, int b) {
        int k0 = t * 32;
#pragma unroll
        for (int j = 0; j < 2; ++j) {
            gload_lds16(A  + asrc[j] + k0, &As[b][(tid + 256 * j) * 8]);
            gload_lds16(Bt + bsrc[j] + k0, &Bs[b][(tid + 256 * j) * 8]);
        }
    };

    auto COMPUTE = [&](int b) {
        bf16x8 af[4], bfr[4];
#pragma unroll
        for (int m = 0; m < 4; ++m) {
            int r = wr + m * 16 + la;
            af[m] = *reinterpret_cast<const bf16x8*>(&As[b][(r * 4 + (kc ^ ((r >> 1) & 3))) * 8]);
        }
#pragma unroll
        for (int n = 0; n < 4; ++n) {
            int r = wc + n * 16 + la;
            bfr[n] = *reinterpret_cast<const bf16x8*>(&Bs[b][(r * 4 + (kc ^ ((r >> 1) & 3))) * 8]);
        }
#pragma unroll
        for (int m = 0; m < 4; ++m)
#pragma unroll
            for (int n = 0; n < 4; ++n)
                acc[m][n] = __builtin_amdgcn_mfma_f32_16x16x32_bf16(af[m], bfr[n], acc[m][n], 0, 0, 0);
    };

    const int nk = K / 32;
    STAGE(0, 0);
    STAGE(1, 1);
    asm volatile("s_waitcnt vmcnt(4)" ::: "memory");   // tile 0 landed; tile 1 in flight
    __builtin_amdgcn_s_barrier();
    for (int t = 0; t < nk; ++t) {
        if (t + 2 < nk) STAGE(t + 2, (t + 2) % 3);     // overwrites tile t-1's buffer
        COMPUTE(t % 3);
        if (t + 1 < nk) {
            if (t + 2 < nk) asm volatile("s_waitcnt vmcnt(4)" ::: "memory"); // t+1 landed
            else            asm volatile("s_waitcnt vmcnt(0)" ::: "memory");
            __builtin_amdgcn_s_barrier();
        }
    }

    // epilogue: C/D layout col = lane&15, row = (lane>>4)*4 + j (HW-verified)
#pragma unroll
    for (int m = 0; m < 4; ++m) {
        int rbase = wr + m * 16 + (lane >> 4) * 4;
#pragma unroll
        for (int n = 0; n < 4; ++n) {
            int gcol = n0 + wc + n * 16 + la;
            float bi = bias[(size_t)e * NCOL + gcol];
#pragma unroll
            for (int jj = 0; jj < 4; ++jj) {
                int entry = m0 + rbase + jj;
                if (entry < cnt_e) {
                    float v = acc[m][n][jj] + bi;
                    if (MODE == 0) {
                        // jax.nn.gelu approximate=True (tanh form)
                        float u = 0.7978845608028654f * (v + 0.044715f * v * v * v);
                        float g = 0.5f * v * (1.f + tanhf(u));
                        hout[(size_t)(offs_e + entry) * NCOL + gcol] = f2bf(g);
                    } else {
                        int tok  = tok_list[e * N_TOK + entry];
                        float w  = w_list  [e * N_TOK + entry];
                        atomicAdd(&out[(size_t)tok * NCOL + gcol], w * v);
                    }
                }
            }
        }
    }
}

extern "C" void kernel_launch(void* const* d_in, const int* in_sizes, int n_in,
                              void* d_out, int out_size, void* d_ws, size_t ws_size,
                              hipStream_t stream)
{
    const float* x  = (const float*)d_in[0];
    const float* Wr = (const float*)d_in[1];
    const float* br = (const float*)d_in[2];
    const float* W1 = (const float*)d_in[3];
    const float* b1 = (const float*)d_in[4];
    const float* W2 = (const float*)d_in[5];
    const float* b2 = (const float*)d_in[6];
    float* out = (float*)d_out;

    // workspace layout (~153 MB total)
    char* ws = (char*)d_ws;
    size_t off = 0;
    auto alloc = [&](size_t bytes) -> void* {
        void* p = ws + off;
        off = (off + bytes + 255) & ~(size_t)255;
        return p;
    };
    ushort_t* xb  = (ushort_t*)alloc((size_t)N_TOK * DIM * 2);            // 16 MB
    ushort_t* w1t = (ushort_t*)alloc((size_t)NE * DIM * FF * 2);          // 32 MB  [E][F][D]
    ushort_t* w2t = (ushort_t*)alloc((size_t)NE * DIM * FF * 2);          // 32 MB  [E][D][F]
    ushort_t* h   = (ushort_t*)alloc(((size_t)2 * N_TOK + 128) * FF * 2); // 64.5 MB (+slack rows)
    int*      cnt = (int*)alloc(NE * sizeof(int));
    int*      offs= (int*)alloc((NE + 1) * sizeof(int));
    int*   tok_list = (int*)alloc((size_t)NE * N_TOK * sizeof(int));
    float* w_list   = (float*)alloc((size_t)NE * N_TOK * sizeof(float));
    (void)ws_size; (void)in_sizes; (void)n_in;

    hipMemsetAsync(out, 0, (size_t)out_size * sizeof(float), stream);
    hipMemsetAsync(cnt, 0, NE * sizeof(int), stream);

    convert_x_kernel<<<(N_TOK * DIM) / (8 * 256), 256, 0, stream>>>(x, xb);
    transpose_conv_kernel<<<dim3(FF / 32, DIM / 32, NE), dim3(32, 8), 0, stream>>>(W1, w1t, DIM, FF);
    transpose_conv_kernel<<<dim3(DIM / 32, FF / 32, NE), dim3(32, 8), 0, stream>>>(W2, w2t, FF, DIM);
    router_kernel<<<N_TOK / 64, 256, 0, stream>>>(x, Wr, br, cnt, tok_list, w_list);
    scan_kernel<<<1, 64, 0, stream>>>(cnt, offs);

    moe_gemm_kernel<0><<<dim3(64 * (FF / 128), 1, NE), 256, 0, stream>>>(
        xb, w1t, b1, cnt, offs, tok_list, w_list, h, nullptr, DIM, FF);
    moe_gemm_kernel<1><<<dim3(64 * (DIM / 128), 1, NE), 256, 0, stream>>>(
        h, w2t, b2, cnt, offs, tok_list, w_list, nullptr, out, FF, DIM);
}

// Round 7
// 527.358 us; speedup vs baseline: 1.5751x; 1.0750x over previous
//
#include <hip/hip_runtime.h>
#include <hip/hip_bf16.h>

// MoE top-2 of 8 experts. N=8192 tokens, D=1024, F=2048.
// R7: (a) GEMM K-loop restored EXACTLY to R4's measured-best form
//     (3 LDS buffers, vmcnt(4);barrier;STAGE(t+2);COMPUTE(t), chunked XCD
//     swizzle on both modes). (b) NEW: A rows pre-gathered+converted into a
//     contiguous per-expert xpack (fuses f32->bf16, deletes convert_x/xb),
//     so GEMM1 staging streams contiguous rows like GEMM2.

#define N_TOK 8192
#define DIM   1024
#define FF    2048
#define NE    8

typedef unsigned short ushort_t;
typedef __bf16 bf16x8 __attribute__((ext_vector_type(8)));
typedef float  f32x4  __attribute__((ext_vector_type(4)));
typedef unsigned short u16x8 __attribute__((ext_vector_type(8)));

__device__ __forceinline__ ushort_t f2bf(float f) {
    union { float f; unsigned int u; } v; v.f = f;
    unsigned int r = (v.u + 0x7FFFu + ((v.u >> 16) & 1u)) >> 16;  // RNE
    return (ushort_t)r;
}

__device__ __forceinline__ void gload_lds16(const ushort_t* g, ushort_t* l) {
    __builtin_amdgcn_global_load_lds(
        (const __attribute__((address_space(1))) void*)g,
        (__attribute__((address_space(3))) void*)l,
        16, 0, 0);
}

// ---------------- tiled transpose + convert: in [E][R][C] f32 -> out [E][C][R] bf16 ----
__global__ void transpose_conv_kernel(
    const float* __restrict__ in, ushort_t* __restrict__ out, int R, int C)
{
    __shared__ float tile[32][33];
    const int e = blockIdx.z;
    const float* I = in + (size_t)e * R * C;
    ushort_t*    O = out + (size_t)e * R * C;
    const int c0 = blockIdx.x * 32, r0 = blockIdx.y * 32;
    const int tx = threadIdx.x, ty = threadIdx.y;   // 32 x 8
#pragma unroll
    for (int j = 0; j < 32; j += 8)
        tile[ty + j][tx] = I[(size_t)(r0 + ty + j) * C + (c0 + tx)];
    __syncthreads();
#pragma unroll
    for (int j = 0; j < 32; j += 8)
        O[(size_t)(c0 + ty + j) * R + (r0 + tx)] = f2bf(tile[tx][ty + j]);
}

// ---------------- router: 128 blocks x 64 tokens; ballot ranking, 8 atomics/blk ----
__global__ __launch_bounds__(256) void router_kernel(
    const float* __restrict__ x, const float* __restrict__ Wr, const float* __restrict__ br,
    int* __restrict__ cnt, int* __restrict__ tok_list, float* __restrict__ w_list)
{
    __shared__ int   se0[64], se1[64];
    __shared__ float sw0[64], sw1[64];

    const int wid  = threadIdx.x >> 6;
    const int lane = threadIdx.x & 63;
    const int tblk = blockIdx.x * 64;

    for (int i = 0; i < 16; ++i) {
        const int li = wid * 16 + i;            // token slot in block
        const int t  = tblk + li;
        const float* xr = x + (size_t)t * DIM;

        float acc[NE];
#pragma unroll
        for (int e = 0; e < NE; ++e) acc[e] = 0.f;
        for (int d = lane; d < DIM; d += 64) {
            float xv = xr[d];
            const float4* w4 = reinterpret_cast<const float4*>(Wr + (size_t)d * NE);
            float4 w0 = w4[0], w1 = w4[1];
            acc[0] += xv * w0.x; acc[1] += xv * w0.y; acc[2] += xv * w0.z; acc[3] += xv * w0.w;
            acc[4] += xv * w1.x; acc[5] += xv * w1.y; acc[6] += xv * w1.z; acc[7] += xv * w1.w;
        }
#pragma unroll
        for (int e = 0; e < NE; ++e) {
            for (int off = 32; off > 0; off >>= 1)
                acc[e] += __shfl_down(acc[e], off, 64);
        }
        if (lane == 0) {
            float l[NE];
#pragma unroll
            for (int e = 0; e < NE; ++e) l[e] = acc[e] + br[e];
            float mx = l[0];
#pragma unroll
            for (int e = 1; e < NE; ++e) mx = fmaxf(mx, l[e]);
            float p[NE], s = 0.f;
#pragma unroll
            for (int e = 0; e < NE; ++e) { p[e] = expf(l[e] - mx); s += p[e]; }
            float inv = 1.f / s;
            // top-2, lowest-index-on-tie (strict >) to match jax.lax.top_k
            int e0 = 0;
#pragma unroll
            for (int e = 1; e < NE; ++e) if (l[e] > l[e0]) e0 = e;
            int e1 = (e0 == 0) ? 1 : 0;
#pragma unroll
            for (int e = 0; e < NE; ++e) if (e != e0 && l[e] > l[e1]) e1 = e;
            se0[li] = e0; sw0[li] = p[e0] * inv;
            se1[li] = e1; sw1[li] = p[e1] * inv;
        }
    }
    __syncthreads();

    // wave 0: rank 64 tokens x 2 slots per expert, reserve ranges, scatter
    if (threadIdx.x < 64) {
        const int t  = tblk + lane;
        const int e0 = se0[lane], e1 = se1[lane];
        const unsigned long long below = ((unsigned long long)1 << lane) - 1;
        int p0 = 0, p1 = 0;
#pragma unroll
        for (int e = 0; e < NE; ++e) {
            unsigned long long m0 = __ballot(e0 == e);
            unsigned long long m1 = __ballot(e1 == e);
            int c = __popcll(m0) + __popcll(m1);
            int b = 0;
            if (lane == e && c) b = atomicAdd(&cnt[e], c);
            b = __shfl(b, e, 64);
            if (e0 == e) p0 = b + __popcll(m0 & below);
            if (e1 == e) p1 = b + __popcll(m0) + __popcll(m1 & below);
        }
        tok_list[e0 * N_TOK + p0] = t;  w_list[e0 * N_TOK + p0] = sw0[lane];
        tok_list[e1 * N_TOK + p1] = t;  w_list[e1 * N_TOK + p1] = sw1[lane];
    }
}

__global__ void scan_kernel(const int* __restrict__ cnt, int* __restrict__ offs)
{
    if (threadIdx.x == 0 && blockIdx.x == 0) {
        int s = 0;
        for (int e = 0; e < NE; ++e) { offs[e] = s; s += cnt[e]; }
        offs[NE] = s;
    }
}

// ---------------- gather+convert A: xpack[row] = bf16(x[tok(row)]), contiguous ----
__global__ __launch_bounds__(256) void gather_a_kernel(
    const float* __restrict__ x, const int* __restrict__ offs,
    const int* __restrict__ tok_list, ushort_t* __restrict__ xpack)
{
    const int c   = blockIdx.x * 256 + threadIdx.x;   // one 8-elem chunk
    const int row = c >> 7;                           // 128 chunks per row
    int e = 0;
#pragma unroll
    for (int k = 1; k < NE; ++k) e += (row >= offs[k]);
    const int tok = tok_list[e * N_TOK + (row - offs[e])];
    const int d0  = (c & 127) << 3;
    const float* src = x + ((size_t)tok << 10) + d0;
    float4 a = *reinterpret_cast<const float4*>(src);
    float4 b = *reinterpret_cast<const float4*>(src + 4);
    u16x8 o;
    o[0] = f2bf(a.x); o[1] = f2bf(a.y); o[2] = f2bf(a.z); o[3] = f2bf(a.w);
    o[4] = f2bf(b.x); o[5] = f2bf(b.y); o[6] = f2bf(b.z); o[7] = f2bf(b.w);
    *reinterpret_cast<u16x8*>(xpack + ((size_t)row << 10) + d0) = o;
}

// ---------------- grouped GEMM, 128x128 tile, BK=32, 4 waves (2x2), acc 4x4 ----
// EXACT R4 structure: 3 LDS buffers, 2-deep prefetch,
// loop body = vmcnt(4); barrier; STAGE(t+2); COMPUTE(t).
// A is contiguous per expert for BOTH modes (xpack for MODE 0, h for MODE 1).
// LDS slot c holds global (row=c>>2, chunk=(c&3)^((row>>1)&3)); read same XOR.
template <int MODE>
__global__ __launch_bounds__(256) void moe_gemm_kernel(
    const ushort_t* __restrict__ A,     // [16384+slack][K] packed rows
    const ushort_t* __restrict__ Bt,    // [NE][NCOL][K] bf16 (K contiguous)
    const float*    __restrict__ bias,  // [NE][NCOL]
    const int*      __restrict__ cnt,
    const int*      __restrict__ offs,
    const int*      __restrict__ tok_list,
    const float*    __restrict__ w_list,
    ushort_t*       __restrict__ hout,
    float*          __restrict__ out,
    int K, int NCOL)
{
    const int e = blockIdx.z;
    const int cnt_e = cnt[e];

    const int cpx = gridDim.x >> 3;   // chunked XCD swizzle (bijective)
    const int wg  = (blockIdx.x & 7) * cpx + (blockIdx.x >> 3);
    const int mb  = wg & 63;           // 64 m-tiles (8192/128)
    const int nb  = wg >> 6;

    const int m0 = mb * 128;
    if (m0 >= cnt_e) return;           // early-exit unused tiles
    const int n0 = nb * 128;
    const int offs_e = offs[e];

    __shared__ ushort_t As[3][128 * 32];
    __shared__ ushort_t Bs[3][128 * 32];

    const int tid = threadIdx.x;

    // per-thread global source offsets (elements); XOR-swizzled chunk within row
    size_t asrc[2], bsrc[2];
#pragma unroll
    for (int j = 0; j < 2; ++j) {
        int c = tid + 256 * j;
        int row   = c >> 2;
        int chunk = (c & 3) ^ ((row >> 1) & 3);
        int entry = m0 + row;
        size_t arow;
        if (MODE == 0) {
            arow = (entry < cnt_e) ? (size_t)(offs_e + entry) * K : 0;  // packed xpack rows
        } else {
            arow = (size_t)(offs_e + entry) * K;   // slack rows allocated in h
        }
        asrc[j] = arow + (size_t)chunk * 8;
        int col = n0 + row;
        bsrc[j] = ((size_t)e * NCOL + col) * K + (size_t)chunk * 8;
    }

    f32x4 acc[4][4];
#pragma unroll
    for (int m = 0; m < 4; ++m)
#pragma unroll
        for (int n = 0; n < 4; ++n)
            acc[m][n] = (f32x4){0.f, 0.f, 0.f, 0.f};

    const int lane = tid & 63;
    const int wid  = tid >> 6;
    const int wr = (wid >> 1) * 64;
    const int wc = (wid & 1) * 64;
    const int la = lane & 15;
    const int kc = lane >> 4;          // k-chunk 0..3 owned by this lane group

    auto STAGE = [&](int t, int b) {
        int k0 = t * 32;
#pragma unroll
        for (int j = 0; j < 2; ++j) {
            gload_lds16(A  + asrc[j] + k0, &As[b][(tid + 256 * j) * 8]);
            gload_lds16(Bt + bsrc[j] + k0, &Bs[b][(tid + 256 * j) * 8]);
        }
    };

    auto COMPUTE = [&](int b) {
        bf16x8 af[4], bfr[4];
#pragma unroll
        for (int m = 0; m < 4; ++m) {
            int r = wr + m * 16 + la;
            af[m] = *reinterpret_cast<const bf16x8*>(&As[b][(r * 4 + (kc ^ ((r >> 1) & 3))) * 8]);
        }
#pragma unroll
        for (int n = 0; n < 4; ++n) {
            int r = wc + n * 16 + la;
            bfr[n] = *reinterpret_cast<const bf16x8*>(&Bs[b][(r * 4 + (kc ^ ((r >> 1) & 3))) * 8]);
        }
#pragma unroll
        for (int m = 0; m < 4; ++m)
#pragma unroll
            for (int n = 0; n < 4; ++n)
                acc[m][n] = __builtin_amdgcn_mfma_f32_16x16x32_bf16(af[m], bfr[n], acc[m][n], 0, 0, 0);
    };

    const int nk = K / 32;
    STAGE(0, 0);
    STAGE(1, 1);
    for (int t = 0; t < nk - 1; ++t) {
        asm volatile("s_waitcnt vmcnt(4)" ::: "memory");
        __builtin_amdgcn_s_barrier();
        if (t + 2 < nk) STAGE(t + 2, (t + 2) % 3);
        COMPUTE(t % 3);
    }
    asm volatile("s_waitcnt vmcnt(0)" ::: "memory");
    __builtin_amdgcn_s_barrier();
    COMPUTE((nk - 1) % 3);

    // epilogue: C/D layout col = lane&15, row = (lane>>4)*4 + j (HW-verified)
#pragma unroll
    for (int m = 0; m < 4; ++m) {
        int rbase = wr + m * 16 + (lane >> 4) * 4;
#pragma unroll
        for (int n = 0; n < 4; ++n) {
            int gcol = n0 + wc + n * 16 + la;
            float bi = bias[(size_t)e * NCOL + gcol];
#pragma unroll
            for (int jj = 0; jj < 4; ++jj) {
                int entry = m0 + rbase + jj;
                if (entry < cnt_e) {
                    float v = acc[m][n][jj] + bi;
                    if (MODE == 0) {
                        // jax.nn.gelu approximate=True (tanh form)
                        float u = 0.7978845608028654f * (v + 0.044715f * v * v * v);
                        float g = 0.5f * v * (1.f + tanhf(u));
                        hout[(size_t)(offs_e + entry) * NCOL + gcol] = f2bf(g);
                    } else {
                        int tok  = tok_list[e * N_TOK + entry];
                        float w  = w_list  [e * N_TOK + entry];
                        atomicAdd(&out[(size_t)tok * NCOL + gcol], w * v);
                    }
                }
            }
        }
    }
}

extern "C" void kernel_launch(void* const* d_in, const int* in_sizes, int n_in,
                              void* d_out, int out_size, void* d_ws, size_t ws_size,
                              hipStream_t stream)
{
    const float* x  = (const float*)d_in[0];
    const float* Wr = (const float*)d_in[1];
    const float* br = (const float*)d_in[2];
    const float* W1 = (const float*)d_in[3];
    const float* b1 = (const float*)d_in[4];
    const float* W2 = (const float*)d_in[5];
    const float* b2 = (const float*)d_in[6];
    float* out = (float*)d_out;

    // workspace layout (~161 MB total)
    char* ws = (char*)d_ws;
    size_t off = 0;
    auto alloc = [&](size_t bytes) -> void* {
        void* p = ws + off;
        off = (off + bytes + 255) & ~(size_t)255;
        return p;
    };
    ushort_t* w1t = (ushort_t*)alloc((size_t)NE * DIM * FF * 2);          // 32 MB  [E][F][D]
    ushort_t* w2t = (ushort_t*)alloc((size_t)NE * DIM * FF * 2);          // 32 MB  [E][D][F]
    ushort_t* xpack = (ushort_t*)alloc((size_t)2 * N_TOK * DIM * 2);      // 32 MB packed A
    ushort_t* h   = (ushort_t*)alloc(((size_t)2 * N_TOK + 128) * FF * 2); // 64.5 MB (+slack rows)
    int*      cnt = (int*)alloc(NE * sizeof(int));
    int*      offs= (int*)alloc((NE + 1) * sizeof(int));
    int*   tok_list = (int*)alloc((size_t)NE * N_TOK * sizeof(int));
    float* w_list   = (float*)alloc((size_t)NE * N_TOK * sizeof(float));
    (void)ws_size; (void)in_sizes; (void)n_in;

    hipMemsetAsync(out, 0, (size_t)out_size * sizeof(float), stream);
    hipMemsetAsync(cnt, 0, NE * sizeof(int), stream);

    transpose_conv_kernel<<<dim3(FF / 32, DIM / 32, NE), dim3(32, 8), 0, stream>>>(W1, w1t, DIM, FF);
    transpose_conv_kernel<<<dim3(DIM / 32, FF / 32, NE), dim3(32, 8), 0, stream>>>(W2, w2t, FF, DIM);
    router_kernel<<<N_TOK / 64, 256, 0, stream>>>(x, Wr, br, cnt, tok_list, w_list);
    scan_kernel<<<1, 64, 0, stream>>>(cnt, offs);
    gather_a_kernel<<<(2 * N_TOK * DIM) / (8 * 256), 256, 0, stream>>>(x, offs, tok_list, xpack);

    moe_gemm_kernel<0><<<dim3(64 * (FF / 128), 1, NE), 256, 0, stream>>>(
        xpack, w1t, b1, cnt, offs, tok_list, w_list, h, nullptr, DIM, FF);
    moe_gemm_kernel<1><<<dim3(64 * (DIM / 128), 1, NE), 256, 0, stream>>>(
        h, w2t, b2, cnt, offs, tok_list, w_list, nullptr, out, FF, DIM);
}